// Round 6
// baseline (1332.047 us; speedup 1.0000x reference)
//
#include <hip/hip_runtime.h>

typedef __attribute__((ext_vector_type(8))) short short8;
typedef __attribute__((ext_vector_type(4))) float floatx4;

__device__ __forceinline__ float b2f(unsigned short u) {
  union { unsigned int i; float f; } c; c.i = ((unsigned int)u) << 16; return c.f;
}
__device__ __forceinline__ unsigned short f2b(float f) {
  union { float f; unsigned int i; } c; c.f = f;
  unsigned int i = c.i;
  return (unsigned short)((i + 0x7FFFu + ((i >> 16) & 1u)) >> 16);
}
__device__ __forceinline__ float elu_f(float x) {
  return x > 0.f ? x : (expf(x) - 1.f);
}
__device__ __forceinline__ float silu_f(float x) {
  return x / (1.f + expf(-x));
}
__device__ __forceinline__ void async16(const unsigned short* g, unsigned short* l) {
  __builtin_amdgcn_global_load_lds(
      (const __attribute__((address_space(1))) void*)g,
      (__attribute__((address_space(3))) void*)l, 16, 0, 0);
}
__device__ __forceinline__ floatx4 mfma16(short8 a, short8 b, floatx4 c) {
  return __builtin_amdgcn_mfma_f32_16x16x32_bf16(a, b, c, 0, 0, 0);
}

// ---------------- dtype detector ----------------
__global__ __launch_bounds__(256) void detect_dtype(
    const unsigned int* __restrict__ x, int* __restrict__ cnt) {
  int t = threadIdx.x;
  int c = 0;
  for (int i = t; i < 4096; i += 256) {
    unsigned int lo = x[i] & 0xFFFFu;
    unsigned int e = (lo >> 7) & 0xFFu;
    if (e >= 0x70u && e <= 0x8Fu) c++;
  }
#pragma unroll
  for (int off = 32; off > 0; off >>= 1) c += __shfl_down(c, off, 64);
  if ((t & 63) == 0) atomicAdd(cnt, c);
}
__device__ __forceinline__ bool is_f32(const int* flag) { return flag[0] < 2048; }

// ---------------- x -> bf16 normalize (only writes on f32 path) ----------------
__global__ __launch_bounds__(256) void convert_x(
    const void* __restrict__ x, unsigned short* __restrict__ xb,
    const int* __restrict__ flag) {
  if (!is_f32(flag)) return;
  size_t i = ((size_t)blockIdx.x * 256 + threadIdx.x) * 8;
  const float* xf = (const float*)x;
  float4 a = *(const float4*)(xf + i);
  float4 b = *(const float4*)(xf + i + 4);
  unsigned short p[8] = {f2b(a.x), f2b(a.y), f2b(a.z), f2b(a.w),
                         f2b(b.x), f2b(b.y), f2b(b.z), f2b(b.w)};
  *(uint4*)(xb + i) = *(uint4*)p;
}

// ---------------- weight transpose (2048x2048) -> bf16 ----------------
__global__ __launch_bounds__(256) void transpose2048(
    const void* __restrict__ src, unsigned short* __restrict__ dst,
    const int* __restrict__ flag) {
  const bool f32 = is_f32(flag);
  __shared__ unsigned short tile[32][33];
  int bx = blockIdx.x * 32;
  int by = blockIdx.y * 32;
  int tx = threadIdx.x & 31;
  int ty = threadIdx.x >> 5;
  for (int i = ty; i < 32; i += 8) {
    size_t idx = (size_t)(by + i) * 2048 + bx + tx;
    tile[i][tx] = f32 ? f2b(((const float*)src)[idx]) : ((const unsigned short*)src)[idx];
  }
  __syncthreads();
  for (int i = ty; i < 32; i += 8)
    dst[(size_t)(bx + i) * 2048 + by + tx] = tile[tx][i];
}

// ---------------- GEMM 256x256 tile, 1024 threads (16 waves, 4 waves/SIMD) ----------------
// C = act(A @ WT^T + bias).  act: 0=none, 1=silu, 2=elu.
// grid: (Nc/256, M/256) linearized + XCD-chunked.  16 waves in 4M x 4N grid,
// per-wave output 64x64, acc[4][4] = 64 AGPR.
// R5 showed zero read/MFMA pipe overlap (tile window = serial sum of phases,
// VGPR=52 => compiler never hoisted ks1 loads above ks0 MFMAs).  This round:
// load ALL 16 fragments (both ks) into registers, THEN issue all 32 MFMAs —
// the compiler's counted lgkmcnt lets ks0 MFMAs overlap ks1's in-flight
// ds_reads (+32 VGPR, still < 128 so 4 waves/SIMD holds).  setprio(1) around
// the MFMA cluster (T5): waves now sit at different micro-phases, so the CU
// scheduler can prefer MFMA-ready waves over read-issuing ones.
// LDS: 2 dbuf x {A,B} x {ks0,ks1} chunks of 256x32 bf16 = 128 KiB (1 block/CU).
// One vmcnt(0)+s_barrier per K-tile (R3: finer cadence neutral).  Chunk layout
// XOR-swizzled (qf = quad ^ ((row>>1)&3)): linear LDS dest for global_load_lds
// + pre-swizzled GLOBAL source + same XOR on reads (0 conflicts, verified R2).
__global__ __launch_bounds__(1024) void gemm256(
    const unsigned short* __restrict__ A0,
    const unsigned short* __restrict__ A1, int a_sel,
    const unsigned short* __restrict__ WT,
    const void* __restrict__ bias,
    void* __restrict__ C, int c_ext,
    int K, int Nc, int act, const int* __restrict__ flag) {
  const bool f32 = is_f32(flag);
  const unsigned short* A = (a_sel && f32) ? A1 : A0;
  __shared__ __align__(16) unsigned short lds[8 * 8192];  // 128 KiB
#define CH(b, m, ks) (lds + ((((b)*2 + (m)) * 2 + (ks)) * 8192))
  const int nbx = gridDim.x;                 // 8
  const int flat = blockIdx.y * nbx + blockIdx.x;
  const int nwg = nbx * gridDim.y;           // 512, divisible by 8
  const int cpx = nwg >> 3;
  const int nf = (flat & 7) * cpx + (flat >> 3);
  const int bn = (nf % nbx) * 256;
  const int bm = (nf / nbx) * 256;
  const int t = threadIdx.x;
  const int lane = t & 63;
  const int wave = t >> 6;            // 0..15
  const int lm = lane & 15;
  const int quad = lane >> 4;
  const int wm = (wave >> 2) * 64;    // 4 M-groups of 64
  const int wn = (wave & 3) * 64;     // 4 N-groups of 64
  const int srow = lane >> 2;         // staging: 4 lanes per 32-col row
  const int scol = (((lane & 3) ^ ((lane >> 3) & 3)) * 8);
  const int rq = (quad ^ ((lm >> 1) & 3)) * 8;
  const int NT = K >> 6;

  floatx4 acc[4][4] = {};

  // each wave stages rows [wave*16, wave*16+16) of each 256x32 chunk
  auto stageA = [&](int kt, int ks, unsigned short* ch) {
    int rr = wave * 16;
    async16(A + (size_t)(bm + rr + srow) * K + kt + ks * 32 + scol, ch + rr * 32);
  };
  auto stageB = [&](int kt, int ks, unsigned short* ch) {
    int rr = wave * 16;
    async16(WT + (size_t)(bn + rr + srow) * K + kt + ks * 32 + scol, ch + rr * 32);
  };

  // prologue: stage tile 0 into buffer 0
  stageA(0, 0, CH(0, 0, 0));
  stageB(0, 0, CH(0, 1, 0));
  stageA(0, 1, CH(0, 0, 1));
  stageB(0, 1, CH(0, 1, 1));
  asm volatile("s_waitcnt vmcnt(0)" ::: "memory");
  asm volatile("s_barrier" ::: "memory");

  for (int ti = 0; ti < NT; ++ti) {
    const int buf = ti & 1, nb = buf ^ 1;
    const int ktn = (ti + 1 < NT ? ti + 1 : ti) << 6;

    // issue all next-tile staging first; vmcnt(0) at tile end is then ~free
    stageA(ktn, 0, CH(nb, 0, 0));
    stageB(ktn, 0, CH(nb, 1, 0));
    stageA(ktn, 1, CH(nb, 0, 1));
    stageB(ktn, 1, CH(nb, 1, 1));

    // load ALL fragments (both ks halves) before any MFMA: ks1 reads stay in
    // flight under ks0's MFMAs via the compiler's counted lgkmcnt waits.
    short8 af[2][4], bf[2][4];
#pragma unroll
    for (int ks = 0; ks < 2; ++ks) {
      const unsigned short* cA = CH(buf, 0, ks);
      const unsigned short* cB = CH(buf, 1, ks);
#pragma unroll
      for (int mi = 0; mi < 4; ++mi)
        af[ks][mi] = *(const short8*)(cA + (wm + mi * 16 + lm) * 32 + rq);
#pragma unroll
      for (int ni = 0; ni < 4; ++ni)
        bf[ks][ni] = *(const short8*)(cB + (wn + ni * 16 + lm) * 32 + rq);
    }
    __builtin_amdgcn_s_setprio(1);
#pragma unroll
    for (int ks = 0; ks < 2; ++ks)
#pragma unroll
      for (int mi = 0; mi < 4; ++mi)
#pragma unroll
        for (int ni = 0; ni < 4; ++ni)
          acc[mi][ni] = mfma16(af[ks][mi], bf[ks][ni], acc[mi][ni]);
    __builtin_amdgcn_s_setprio(0);

    asm volatile("s_waitcnt vmcnt(0)" ::: "memory");
    asm volatile("s_barrier" ::: "memory");
  }

  // ---- epilogue ----
  if (c_ext && f32) {
#pragma unroll
    for (int ni = 0; ni < 4; ++ni) {
      int col = bn + wn + ni * 16 + lm;
      float bv = ((const float*)bias)[col];
#pragma unroll
      for (int mi = 0; mi < 4; ++mi) {
#pragma unroll
        for (int r = 0; r < 4; ++r) {
          int row = bm + wm + mi * 16 + quad * 4 + r;
          float v = acc[mi][ni][r] + bv;
          if (act == 1) v = silu_f(v);
          else if (act == 2) v = elu_f(v);
          ((float*)C)[(size_t)row * Nc + col] = v;
        }
      }
    }
  } else {
    // bf16 path: LDS bounce for full-row coalesced uint4 stores
    unsigned short* ot = lds;
#pragma unroll
    for (int ni = 0; ni < 4; ++ni) {
      int col = wn + ni * 16 + lm;
      float bv = f32 ? ((const float*)bias)[bn + col]
                     : b2f(((const unsigned short*)bias)[bn + col]);
#pragma unroll
      for (int mi = 0; mi < 4; ++mi) {
        int rbase = wm + mi * 16 + quad * 4;
#pragma unroll
        for (int r = 0; r < 4; ++r) {
          float v = acc[mi][ni][r] + bv;
          if (act == 1) v = silu_f(v);
          else if (act == 2) v = elu_f(v);
          ot[(rbase + r) * 256 + (col ^ (quad << 4))] = f2b(v);
        }
      }
    }
    __syncthreads();
    unsigned short* Cs = (unsigned short*)C;
#pragma unroll
    for (int i = 0; i < 8; ++i) {
      int c = t + 1024 * i;   // 8192 chunk ids (256 rows x 32 chunks of 16B)
      int row = c >> 5;
      int k = c & 31;
      int phys = (k * 8) ^ (((row >> 2) & 3) << 4);
      uint4 v = *(const uint4*)&ot[row * 256 + phys];
      *(uint4*)(Cs + (size_t)(bm + row) * Nc + bn + k * 8) = v;
    }
  }
#undef CH
}

// ---------------- kv accumulation: kvT[b,h][e][d] += sum_n EK[n,d] * V[n,e] ----------------
// EK = elu(x@Wqk+bqk) precomputed by the gemm epilogue (act=2).
__global__ __launch_bounds__(256) void kv_accum(
    const unsigned short* __restrict__ EK,
    const unsigned short* __restrict__ V,
    float* __restrict__ kvT, int chunk) {
  const int bh = blockIdx.x;
  const int sp = blockIdx.y;
  const int b = bh >> 4, h = bh & 15;
  __shared__ __align__(16) unsigned short Kt[128][72];
  __shared__ __align__(16) unsigned short Vt[128][72];
  const int t = threadIdx.x;
  const int lane = t & 63, wave = t >> 6;
  const int lm = lane & 15, quad = lane >> 4;
  const int wm = (wave >> 1) * 64, wn = (wave & 1) * 64;
  floatx4 acc[4][4] = {};
  const size_t base = (size_t)b * 4096 * 2048 + (size_t)h * 128;
  const int nl = t & 63;
  const int dg0 = t >> 6;
  for (int n0 = sp * chunk; n0 < (sp + 1) * chunk; n0 += 64) {
#pragma unroll
    for (int i = 0; i < 4; ++i) {
      int dg = dg0 + 4 * i;
      union { uint4 u; unsigned short s[8]; } vk, vv;
      vk.u = *(const uint4*)(EK + base + (size_t)(n0 + nl) * 2048 + dg * 8);
      vv.u = *(const uint4*)(V + base + (size_t)(n0 + nl) * 2048 + dg * 8);
#pragma unroll
      for (int j = 0; j < 8; ++j) {
        Kt[dg * 8 + j][nl] = vk.s[j];
        Vt[dg * 8 + j][nl] = vv.s[j];
      }
    }
    __syncthreads();
#pragma unroll
    for (int ks = 0; ks < 2; ++ks) {
      short8 af[4], bf[4];
#pragma unroll
      for (int mi = 0; mi < 4; ++mi)
        af[mi] = *(const short8*)&Kt[wm + mi * 16 + lm][ks * 32 + quad * 8];
#pragma unroll
      for (int ni = 0; ni < 4; ++ni)
        bf[ni] = *(const short8*)&Vt[wn + ni * 16 + lm][ks * 32 + quad * 8];
#pragma unroll
      for (int mi = 0; mi < 4; ++mi)
#pragma unroll
        for (int ni = 0; ni < 4; ++ni)
          acc[mi][ni] = __builtin_amdgcn_mfma_f32_16x16x32_bf16(
              af[mi], bf[ni], acc[mi][ni], 0, 0, 0);
    }
    __syncthreads();
  }
  float* dst = kvT + (size_t)bh * 128 * 128;
#pragma unroll
  for (int mi = 0; mi < 4; ++mi)
#pragma unroll
    for (int ni = 0; ni < 4; ++ni)
#pragma unroll
      for (int r = 0; r < 4; ++r) {
        int d = wm + mi * 16 + quad * 4 + r;
        int e = wn + ni * 16 + lm;
        atomicAdd(&dst[e * 128 + d], acc[mi][ni][r]);
      }
}

// ---------------- attention out: O[n, h*128+e] = sum_d EK[n,d] * kv[d,e] ----------------
__global__ __launch_bounds__(256) void attn_out(
    const unsigned short* __restrict__ EK,
    const float* __restrict__ kvT,
    unsigned short* __restrict__ O) {
  const int flat0 = blockIdx.y * 16 + blockIdx.x;
  const int nf = (flat0 & 7) * 256 + (flat0 >> 3);  // 2048 blocks, 2048%8==0
  const int h = nf & 15;
  const int bm = (nf >> 4) * 128;
  const int b = bm >> 12;
  const int bh = b * 16 + h;
  __shared__ __align__(16) unsigned short As[128][136];
  __shared__ __align__(16) unsigned short Bs[128][136];
  const int t = threadIdx.x;
  const int lane = t & 63, wave = t >> 6;
  const int lm = lane & 15, quad = lane >> 4;
  const int wm = (wave >> 1) * 64, wn = (wave & 1) * 64;
  {
    const int r0 = t >> 4;
    const int g = t & 15;
#pragma unroll
    for (int i = 0; i < 8; ++i) {
      int r = r0 + 16 * i;
      uint4 vq = *(const uint4*)(EK + (size_t)(bm + r) * 2048 + h * 128 + g * 8);
      *(uint4*)&As[r][g * 8] = vq;   // EK pre-activated: pure copy
    }
    const int e0 = t >> 5;
    const int gg = t & 31;
    const float* kvp = kvT + (size_t)bh * 16384;
#pragma unroll
    for (int i = 0; i < 16; ++i) {
      int e = e0 + 8 * i;
      float4 f = *(const float4*)(kvp + e * 128 + gg * 4);
      unsigned short o4[4] = {f2b(f.x), f2b(f.y), f2b(f.z), f2b(f.w)};
      *(uint2*)&Bs[e][gg * 4] = *(uint2*)o4;
    }
  }
  __syncthreads();
  floatx4 acc[4][4] = {};
#pragma unroll
  for (int ks = 0; ks < 4; ++ks) {
    short8 af[4], bf[4];
#pragma unroll
    for (int mi = 0; mi < 4; ++mi)
      af[mi] = *(const short8*)&As[wm + mi * 16 + lm][ks * 32 + quad * 8];
#pragma unroll
    for (int ni = 0; ni < 4; ++ni)
      bf[ni] = *(const short8*)&Bs[wn + ni * 16 + lm][ks * 32 + quad * 8];
#pragma unroll
    for (int mi = 0; mi < 4; ++mi)
#pragma unroll
      for (int ni = 0; ni < 4; ++ni)
        acc[mi][ni] = __builtin_amdgcn_mfma_f32_16x16x32_bf16(
            af[mi], bf[ni], acc[mi][ni], 0, 0, 0);
  }
#pragma unroll
  for (int mi = 0; mi < 4; ++mi)
#pragma unroll
    for (int ni = 0; ni < 4; ++ni)
#pragma unroll
      for (int r = 0; r < 4; ++r) {
        int row = bm + wm + mi * 16 + quad * 4 + r;
        int e = wn + ni * 16 + lm;
        O[(size_t)row * 2048 + h * 128 + e] = f2b(acc[mi][ni][r]);
      }
}

// ---------------- layernorm(O) * U -> T (vectorized: 8 contiguous bf16/thread) ----------------
__global__ __launch_bounds__(256) void ln_mul(
    const unsigned short* __restrict__ O,
    const unsigned short* __restrict__ U,
    const void* __restrict__ g,
    const void* __restrict__ bb,
    unsigned short* __restrict__ T, const int* __restrict__ flag) {
  const bool f32 = is_f32(flag);
  const int row = blockIdx.x;
  const int t = threadIdx.x;
  const size_t base = (size_t)row * 2048 + t * 8;
  union { uint4 u; unsigned short s[8]; } vo, vu;
  vo.u = *(const uint4*)(O + base);
  float vals[8];
  float s = 0.f, s2 = 0.f;
#pragma unroll
  for (int j = 0; j < 8; ++j) {
    float f = b2f(vo.s[j]);
    vals[j] = f;
    s += f;
    s2 += f * f;
  }
#pragma unroll
  for (int off = 32; off > 0; off >>= 1) {
    s += __shfl_down(s, off, 64);
    s2 += __shfl_down(s2, off, 64);
  }
  __shared__ float ps[4], ps2[4];
  int lane = t & 63, wave = t >> 6;
  if (lane == 0) { ps[wave] = s; ps2[wave] = s2; }
  __syncthreads();
  float S = ps[0] + ps[1] + ps[2] + ps[3];
  float S2 = ps2[0] + ps2[1] + ps2[2] + ps2[3];
  float mu = S * (1.f / 2048.f);
  float var = S2 * (1.f / 2048.f) - mu * mu;
  float rs = rsqrtf(var + 1e-5f);
  vu.u = *(const uint4*)(U + base);
  float gv[8], bv[8];
  if (f32) {
    float4 g0 = *(const float4*)((const float*)g + t * 8);
    float4 g1 = *(const float4*)((const float*)g + t * 8 + 4);
    float4 b0 = *(const float4*)((const float*)bb + t * 8);
    float4 b1 = *(const float4*)((const float*)bb + t * 8 + 4);
    gv[0] = g0.x; gv[1] = g0.y; gv[2] = g0.z; gv[3] = g0.w;
    gv[4] = g1.x; gv[5] = g1.y; gv[6] = g1.z; gv[7] = g1.w;
    bv[0] = b0.x; bv[1] = b0.y; bv[2] = b0.z; bv[3] = b0.w;
    bv[4] = b1.x; bv[5] = b1.y; bv[6] = b1.z; bv[7] = b1.w;
  } else {
    union { uint4 u; unsigned short s[8]; } vg, vb;
    vg.u = *(const uint4*)((const unsigned short*)g + t * 8);
    vb.u = *(const uint4*)((const unsigned short*)bb + t * 8);
#pragma unroll
    for (int j = 0; j < 8; ++j) { gv[j] = b2f(vg.s[j]); bv[j] = b2f(vb.s[j]); }
  }
  unsigned short outp[8];
#pragma unroll
  for (int j = 0; j < 8; ++j) {
    float nv = (vals[j] - mu) * rs * gv[j] + bv[j];
    outp[j] = f2b(nv * b2f(vu.s[j]));
  }
  *(uint4*)(T + base) = *(uint4*)outp;
}

extern "C" void kernel_launch(void* const* d_in, const int* in_sizes, int n_in,
                              void* d_out, int out_size, void* d_ws, size_t ws_size,
                              hipStream_t stream) {
  const void* x   = d_in[0];
  const void* Wqk = d_in[1];
  const void* bqk = d_in[2];
  const void* Wv  = d_in[3];
  const void* bv  = d_in[4];
  const void* Wu  = d_in[5];
  const void* bu  = d_in[6];
  const void* Wo  = d_in[7];
  const void* bo  = d_in[8];
  const void* lng = d_in[9];
  const void* lnb = d_in[10];

  char* ws = (char*)d_ws;
  const size_t MB = 1024 * 1024;
  int* flag = (int*)ws;                                   // [0, 1MB)
  unsigned short* WT   = (unsigned short*)(ws + 1 * MB);  // 8 MiB (reused 4x)
  unsigned short* buf0 = (unsigned short*)(ws + 16 * MB); // 64 MiB: EK -> U
  unsigned short* buf1 = (unsigned short*)(ws + 80 * MB); // 64 MiB: V -> O -> T
  float* kvT = (float*)(ws + 144 * MB);                   // 4 MiB
  unsigned short* xb = (unsigned short*)(ws + 148 * MB);  // 64 MiB, touched ONLY on f32 path

  dim3 tb(256);
  dim3 gb(1024);
  dim3 ggrid(8, 64);  // (N/256, M/256)
  hipMemsetAsync(flag, 0, 4096, stream);
  hipMemsetAsync(kvT, 0, (size_t)64 * 128 * 128 * 4, stream);
  detect_dtype<<<1, tb, 0, stream>>>((const unsigned int*)x, flag);
  convert_x<<<16384, tb, 0, stream>>>(x, xb, flag);

  const unsigned short* xs = (const unsigned short*)x;
  // EK = elu(x @ Wqk + bqk)   (elu fused: Q == K, used by both kv_accum & attn_out)
  transpose2048<<<dim3(64, 64), tb, 0, stream>>>(Wqk, WT, flag);
  gemm256<<<ggrid, gb, 0, stream>>>(xs, xb, 1, WT, bqk, buf0, 0, 2048, 2048, 2, flag);
  // V = silu(x @ Wv + bv)
  transpose2048<<<dim3(64, 64), tb, 0, stream>>>(Wv, WT, flag);
  gemm256<<<ggrid, gb, 0, stream>>>(xs, xb, 1, WT, bv, buf1, 0, 2048, 2048, 1, flag);
  // kv = EK^T V
  kv_accum<<<dim3(64, 8), tb, 0, stream>>>(buf0, buf1, kvT, 512);
  // O = EK @ kv  (overwrites V buffer)
  attn_out<<<dim3(16, 128), tb, 0, stream>>>(buf0, kvT, buf1);
  // U = silu(x @ Wu + bu)  (overwrites EK buffer)
  transpose2048<<<dim3(64, 64), tb, 0, stream>>>(Wu, WT, flag);
  gemm256<<<ggrid, gb, 0, stream>>>(xs, xb, 1, WT, bu, buf0, 0, 2048, 2048, 1, flag);
  // T = layernorm(O) * U  (in place over O)
  ln_mul<<<16384, tb, 0, stream>>>(buf1, buf0, lng, lnb, buf1, flag);
  // out = T @ Wo + bo
  transpose2048<<<dim3(64, 64), tb, 0, stream>>>(Wo, WT, flag);
  gemm256<<<ggrid, gb, 0, stream>>>(buf1, buf1, 0, WT, bo, d_out, 1, 2048, 2048, 0, flag);
}

// Round 7
// 1082.390 us; speedup vs baseline: 1.2307x; 1.2307x over previous
//
#include <hip/hip_runtime.h>

typedef __attribute__((ext_vector_type(8))) short short8;
typedef __attribute__((ext_vector_type(4))) float floatx4;

__device__ __forceinline__ float b2f(unsigned short u) {
  union { unsigned int i; float f; } c; c.i = ((unsigned int)u) << 16; return c.f;
}
__device__ __forceinline__ unsigned short f2b(float f) {
  union { float f; unsigned int i; } c; c.f = f;
  unsigned int i = c.i;
  return (unsigned short)((i + 0x7FFFu + ((i >> 16) & 1u)) >> 16);
}
__device__ __forceinline__ float elu_f(float x) {
  return x > 0.f ? x : (expf(x) - 1.f);
}
__device__ __forceinline__ float silu_f(float x) {
  return x / (1.f + expf(-x));
}
__device__ __forceinline__ void async16(const unsigned short* g, unsigned short* l) {
  __builtin_amdgcn_global_load_lds(
      (const __attribute__((address_space(1))) void*)g,
      (__attribute__((address_space(3))) void*)l, 16, 0, 0);
}
__device__ __forceinline__ floatx4 mfma16(short8 a, short8 b, floatx4 c) {
  return __builtin_amdgcn_mfma_f32_16x16x32_bf16(a, b, c, 0, 0, 0);
}

// ---------------- dtype detector ----------------
__global__ __launch_bounds__(256) void detect_dtype(
    const unsigned int* __restrict__ x, int* __restrict__ cnt) {
  int t = threadIdx.x;
  int c = 0;
  for (int i = t; i < 4096; i += 256) {
    unsigned int lo = x[i] & 0xFFFFu;
    unsigned int e = (lo >> 7) & 0xFFu;
    if (e >= 0x70u && e <= 0x8Fu) c++;
  }
#pragma unroll
  for (int off = 32; off > 0; off >>= 1) c += __shfl_down(c, off, 64);
  if ((t & 63) == 0) atomicAdd(cnt, c);
}
__device__ __forceinline__ bool is_f32(const int* flag) { return flag[0] < 2048; }

// ---------------- x -> bf16 normalize (only writes on f32 path) ----------------
__global__ __launch_bounds__(256) void convert_x(
    const void* __restrict__ x, unsigned short* __restrict__ xb,
    const int* __restrict__ flag) {
  if (!is_f32(flag)) return;
  size_t i = ((size_t)blockIdx.x * 256 + threadIdx.x) * 8;
  const float* xf = (const float*)x;
  float4 a = *(const float4*)(xf + i);
  float4 b = *(const float4*)(xf + i + 4);
  unsigned short p[8] = {f2b(a.x), f2b(a.y), f2b(a.z), f2b(a.w),
                         f2b(b.x), f2b(b.y), f2b(b.z), f2b(b.w)};
  *(uint4*)(xb + i) = *(uint4*)p;
}

// ---------------- weight transpose (2048x2048) -> bf16 ----------------
__global__ __launch_bounds__(256) void transpose2048(
    const void* __restrict__ src, unsigned short* __restrict__ dst,
    const int* __restrict__ flag) {
  const bool f32 = is_f32(flag);
  __shared__ unsigned short tile[32][33];
  int bx = blockIdx.x * 32;
  int by = blockIdx.y * 32;
  int tx = threadIdx.x & 31;
  int ty = threadIdx.x >> 5;
  for (int i = ty; i < 32; i += 8) {
    size_t idx = (size_t)(by + i) * 2048 + bx + tx;
    tile[i][tx] = f32 ? f2b(((const float*)src)[idx]) : ((const unsigned short*)src)[idx];
  }
  __syncthreads();
  for (int i = ty; i < 32; i += 8)
    dst[(size_t)(bx + i) * 2048 + by + tx] = tile[tx][i];
}

// ---------------- GEMM 256x256 tile, 1024 threads (16 waves, 4 waves/SIMD) ----------------
// C = act(A @ WT^T + bias).  act: 0=none, 1=silu, 2=elu.
// R5-proven body (153 us, MfmaUtil 39): per-ks fragment load + MFMA, one
// vmcnt(0)+s_barrier per K-tile.  R6's all-fragments preload regressed 58%
// (compiler drained lgkmcnt fully under the larger live set) — reverted.
// NEW: wtr transposed write support.  wtr=1: also write CT[d][m] (=C^T);
// wtr=2: write ONLY CT.  Used so kv_accum can consume EK^T/V^T with pure
// vectorized staging (no per-element LDS transpose).
// LDS: 2 dbuf x {A,B} x {ks0,ks1} chunks of 256x32 bf16 = 128 KiB (1 block/CU).
// Chunk layout XOR-swizzled (qf = quad ^ ((row>>1)&3)): linear LDS dest for
// global_load_lds + pre-swizzled GLOBAL source + same XOR on reads (0 conflicts).
__global__ __launch_bounds__(1024) void gemm256(
    const unsigned short* __restrict__ A0,
    const unsigned short* __restrict__ A1, int a_sel,
    const unsigned short* __restrict__ WT,
    const void* __restrict__ bias,
    void* __restrict__ C, int c_ext,
    unsigned short* __restrict__ CT, int wtr,
    int K, int Nc, int act, const int* __restrict__ flag) {
  const bool f32 = is_f32(flag);
  const unsigned short* A = (a_sel && f32) ? A1 : A0;
  __shared__ __align__(16) unsigned short lds[8 * 8192];  // 128 KiB
#define CH(b, m, ks) (lds + ((((b)*2 + (m)) * 2 + (ks)) * 8192))
  const int nbx = gridDim.x;                 // 8
  const int flat = blockIdx.y * nbx + blockIdx.x;
  const int nwg = nbx * gridDim.y;           // 512, divisible by 8
  const int cpx = nwg >> 3;
  const int nf = (flat & 7) * cpx + (flat >> 3);
  const int bn = (nf % nbx) * 256;
  const int bm = (nf / nbx) * 256;
  const int t = threadIdx.x;
  const int lane = t & 63;
  const int wave = t >> 6;            // 0..15
  const int lm = lane & 15;
  const int quad = lane >> 4;
  const int wm = (wave >> 2) * 64;    // 4 M-groups of 64
  const int wn = (wave & 3) * 64;     // 4 N-groups of 64
  const int srow = lane >> 2;         // staging: 4 lanes per 32-col row
  const int scol = (((lane & 3) ^ ((lane >> 3) & 3)) * 8);
  const int rq = (quad ^ ((lm >> 1) & 3)) * 8;
  const int NT = K >> 6;

  floatx4 acc[4][4] = {};

  auto stageA = [&](int kt, int ks, unsigned short* ch) {
    int rr = wave * 16;
    async16(A + (size_t)(bm + rr + srow) * K + kt + ks * 32 + scol, ch + rr * 32);
  };
  auto stageB = [&](int kt, int ks, unsigned short* ch) {
    int rr = wave * 16;
    async16(WT + (size_t)(bn + rr + srow) * K + kt + ks * 32 + scol, ch + rr * 32);
  };

  // prologue: stage tile 0 into buffer 0
  stageA(0, 0, CH(0, 0, 0));
  stageB(0, 0, CH(0, 1, 0));
  stageA(0, 1, CH(0, 0, 1));
  stageB(0, 1, CH(0, 1, 1));
  asm volatile("s_waitcnt vmcnt(0)" ::: "memory");
  asm volatile("s_barrier" ::: "memory");

  for (int ti = 0; ti < NT; ++ti) {
    const int buf = ti & 1, nb = buf ^ 1;
    const int ktn = (ti + 1 < NT ? ti + 1 : ti) << 6;

    stageA(ktn, 0, CH(nb, 0, 0));
    stageB(ktn, 0, CH(nb, 1, 0));
    stageA(ktn, 1, CH(nb, 0, 1));
    stageB(ktn, 1, CH(nb, 1, 1));

#pragma unroll
    for (int ks = 0; ks < 2; ++ks) {
      const unsigned short* cA = CH(buf, 0, ks);
      const unsigned short* cB = CH(buf, 1, ks);
      short8 af[4], bf[4];
#pragma unroll
      for (int mi = 0; mi < 4; ++mi)
        af[mi] = *(const short8*)(cA + (wm + mi * 16 + lm) * 32 + rq);
#pragma unroll
      for (int ni = 0; ni < 4; ++ni)
        bf[ni] = *(const short8*)(cB + (wn + ni * 16 + lm) * 32 + rq);
#pragma unroll
      for (int mi = 0; mi < 4; ++mi)
#pragma unroll
        for (int ni = 0; ni < 4; ++ni)
          acc[mi][ni] = mfma16(af[mi], bf[ni], acc[mi][ni]);
    }

    asm volatile("s_waitcnt vmcnt(0)" ::: "memory");
    asm volatile("s_barrier" ::: "memory");
  }

  // ---- epilogue ----
  if (c_ext && f32) {
#pragma unroll
    for (int ni = 0; ni < 4; ++ni) {
      int col = bn + wn + ni * 16 + lm;
      float bv = ((const float*)bias)[col];
#pragma unroll
      for (int mi = 0; mi < 4; ++mi) {
#pragma unroll
        for (int r = 0; r < 4; ++r) {
          int row = bm + wm + mi * 16 + quad * 4 + r;
          float v = acc[mi][ni][r] + bv;
          if (act == 1) v = silu_f(v);
          else if (act == 2) v = elu_f(v);
          ((float*)C)[(size_t)row * Nc + col] = v;
        }
      }
    }
  } else {
    // bf16 path: LDS bounce; phys col = col ^ (((row>>2)&3)<<4)
    unsigned short* ot = lds;
#pragma unroll
    for (int ni = 0; ni < 4; ++ni) {
      int col = wn + ni * 16 + lm;
      float bv = f32 ? ((const float*)bias)[bn + col]
                     : b2f(((const unsigned short*)bias)[bn + col]);
#pragma unroll
      for (int mi = 0; mi < 4; ++mi) {
        int rbase = wm + mi * 16 + quad * 4;
#pragma unroll
        for (int r = 0; r < 4; ++r) {
          float v = acc[mi][ni][r] + bv;
          if (act == 1) v = silu_f(v);
          else if (act == 2) v = elu_f(v);
          ot[(rbase + r) * 256 + (col ^ (quad << 4))] = f2b(v);
        }
      }
    }
    __syncthreads();
    if (wtr != 2) {
      unsigned short* Cs = (unsigned short*)C;
#pragma unroll
      for (int i = 0; i < 8; ++i) {
        int c = t + 1024 * i;   // 8192 chunk ids (256 rows x 32 chunks of 16B)
        int row = c >> 5;
        int k = c & 31;
        int phys = (k * 8) ^ (((row >> 2) & 3) << 4);
        uint4 v = *(const uint4*)&ot[row * 256 + phys];
        *(uint4*)(Cs + (size_t)(bm + row) * Nc + bn + k * 8) = v;
      }
    }
    if (wtr != 0) {
      // transposed store: CT[bn+dT][bm + m], row stride Mtot=16384
#pragma unroll
      for (int i = 0; i < 8; ++i) {
        int c2 = t + 1024 * i;          // 8192 chunks
        int dT = c2 >> 5;               // 0..255 (output-col dim)
        int mg = c2 & 31;               // 8-wide m-group
        unsigned short p[8];
#pragma unroll
        for (int j = 0; j < 8; ++j) {
          int m = mg * 8 + j;
          p[j] = ot[m * 256 + (dT ^ (((m >> 2) & 3) << 4))];
        }
        *(uint4*)(CT + (size_t)(bn + dT) * 16384 + bm + mg * 8) = *(uint4*)p;
      }
    }
  }
#undef CH
}

// ---------------- kv accumulation (mini-gemm): kvT[bh][e][d] += sum_n EKT[d][m] * VT[e][m] ----------------
// EKT/VT are [2048][16384] bf16 (transposed activations from the gemm wtr path).
// Block (bh, sp): 256 threads, 4 waves (2d x 2e of 64x64), K-dim = n (chunk per sp).
// Staging = global_load_lds chunks [128][32] with the proven XOR swizzle +
// double buffer — no per-element transpose (was 16 scalar ds_write_b16/thread).
__global__ __launch_bounds__(256) void kv_accum(
    const unsigned short* __restrict__ EKT,
    const unsigned short* __restrict__ VT,
    float* __restrict__ kvT, int chunk) {
  const int bh = blockIdx.x;
  const int sp = blockIdx.y;
  const int b = bh >> 4, h = bh & 15;
  __shared__ __align__(16) unsigned short lds[8 * 4096];  // 64 KiB
#define KCH(bu, m, ks) (lds + ((((bu)*2 + (m)) * 2 + (ks)) * 4096))
  const int t = threadIdx.x;
  const int lane = t & 63, wave = t >> 6;
  const int lm = lane & 15, quad = lane >> 4;
  const int wm = (wave >> 1) * 64, wn = (wave & 1) * 64;
  const int srow = lane >> 2;
  const int scol = (((lane & 3) ^ ((lane >> 3) & 3)) * 8);
  const int rq = (quad ^ ((lm >> 1) & 3)) * 8;
  floatx4 acc[4][4] = {};
  const int n0base = sp * chunk + b * 4096;   // column (m) offset
  const int NI = chunk >> 6;

  auto stage = [&](const unsigned short* src, int n0, int ks, unsigned short* ch) {
#pragma unroll
    for (int c = 0; c < 2; ++c) {
      int rr = c * 64 + wave * 16;
      async16(src + (size_t)(h * 128 + rr + srow) * 16384 + n0 + ks * 32 + scol,
              ch + rr * 32);
    }
  };

  stage(EKT, n0base, 0, KCH(0, 0, 0));
  stage(VT,  n0base, 0, KCH(0, 1, 0));
  stage(EKT, n0base, 1, KCH(0, 0, 1));
  stage(VT,  n0base, 1, KCH(0, 1, 1));
  asm volatile("s_waitcnt vmcnt(0)" ::: "memory");
  asm volatile("s_barrier" ::: "memory");

  for (int ti = 0; ti < NI; ++ti) {
    const int buf = ti & 1, nb = buf ^ 1;
    const int nn = n0base + ((ti + 1 < NI ? ti + 1 : ti) << 6);
    stage(EKT, nn, 0, KCH(nb, 0, 0));
    stage(VT,  nn, 0, KCH(nb, 1, 0));
    stage(EKT, nn, 1, KCH(nb, 0, 1));
    stage(VT,  nn, 1, KCH(nb, 1, 1));
#pragma unroll
    for (int ks = 0; ks < 2; ++ks) {
      const unsigned short* cA = KCH(buf, 0, ks);
      const unsigned short* cB = KCH(buf, 1, ks);
      short8 af[4], bf[4];
#pragma unroll
      for (int mi = 0; mi < 4; ++mi)
        af[mi] = *(const short8*)(cA + (wm + mi * 16 + lm) * 32 + rq);
#pragma unroll
      for (int ni = 0; ni < 4; ++ni)
        bf[ni] = *(const short8*)(cB + (wn + ni * 16 + lm) * 32 + rq);
#pragma unroll
      for (int mi = 0; mi < 4; ++mi)
#pragma unroll
        for (int ni = 0; ni < 4; ++ni)
          acc[mi][ni] = mfma16(af[mi], bf[ni], acc[mi][ni]);
    }
    asm volatile("s_waitcnt vmcnt(0)" ::: "memory");
    asm volatile("s_barrier" ::: "memory");
  }

  float* dst = kvT + (size_t)bh * 128 * 128;
#pragma unroll
  for (int mi = 0; mi < 4; ++mi)
#pragma unroll
    for (int ni = 0; ni < 4; ++ni)
#pragma unroll
      for (int r = 0; r < 4; ++r) {
        int d = wm + mi * 16 + quad * 4 + r;
        int e = wn + ni * 16 + lm;
        atomicAdd(&dst[e * 128 + d], acc[mi][ni][r]);
      }
#undef KCH
}

// ---------------- kvT f32 -> bf16 (once; attn_out then stages pure copies) ----------------
__global__ __launch_bounds__(256) void kv_to_bf16(
    const float* __restrict__ kvT, unsigned short* __restrict__ kvb) {
  size_t i = ((size_t)blockIdx.x * 256 + threadIdx.x) * 8;
  float4 a = *(const float4*)(kvT + i);
  float4 b = *(const float4*)(kvT + i + 4);
  unsigned short p[8] = {f2b(a.x), f2b(a.y), f2b(a.z), f2b(a.w),
                         f2b(b.x), f2b(b.y), f2b(b.z), f2b(b.w)};
  *(uint4*)(kvb + i) = *(uint4*)p;
}

// ---------------- attention out: O[n, h*128+e] = sum_d EK[n,d] * kv[d,e] ----------------
__global__ __launch_bounds__(256) void attn_out(
    const unsigned short* __restrict__ EK,
    const unsigned short* __restrict__ kvb,
    unsigned short* __restrict__ O) {
  const int flat0 = blockIdx.y * 16 + blockIdx.x;
  const int nf = (flat0 & 7) * 256 + (flat0 >> 3);  // 2048 blocks, 2048%8==0
  const int h = nf & 15;
  const int bm = (nf >> 4) * 128;
  const int b = bm >> 12;
  const int bh = b * 16 + h;
  __shared__ __align__(16) unsigned short As[128][136];
  __shared__ __align__(16) unsigned short Bs[128][136];
  const int t = threadIdx.x;
  const int lane = t & 63, wave = t >> 6;
  const int lm = lane & 15, quad = lane >> 4;
  const int wm = (wave >> 1) * 64, wn = (wave & 1) * 64;
  {
    const int r0 = t >> 4;
    const int g = t & 15;
#pragma unroll
    for (int i = 0; i < 8; ++i) {
      int r = r0 + 16 * i;
      uint4 vq = *(const uint4*)(EK + (size_t)(bm + r) * 2048 + h * 128 + g * 8);
      *(uint4*)&As[r][g * 8] = vq;   // EK pre-activated: pure copy
    }
    const unsigned short* kvp = kvb + (size_t)bh * 16384;
#pragma unroll
    for (int i = 0; i < 8; ++i) {
      int c = t + 256 * i;           // 2048 chunks of 16B
      int e = c >> 4, g2 = c & 15;
      *(uint4*)&Bs[e][g2 * 8] = *(const uint4*)(kvp + e * 128 + g2 * 8);
    }
  }
  __syncthreads();
  floatx4 acc[4][4] = {};
#pragma unroll
  for (int ks = 0; ks < 4; ++ks) {
    short8 af[4], bf[4];
#pragma unroll
    for (int mi = 0; mi < 4; ++mi)
      af[mi] = *(const short8*)&As[wm + mi * 16 + lm][ks * 32 + quad * 8];
#pragma unroll
    for (int ni = 0; ni < 4; ++ni)
      bf[ni] = *(const short8*)&Bs[wn + ni * 16 + lm][ks * 32 + quad * 8];
#pragma unroll
    for (int mi = 0; mi < 4; ++mi)
#pragma unroll
      for (int ni = 0; ni < 4; ++ni)
        acc[mi][ni] = __builtin_amdgcn_mfma_f32_16x16x32_bf16(
            af[mi], bf[ni], acc[mi][ni], 0, 0, 0);
  }
#pragma unroll
  for (int mi = 0; mi < 4; ++mi)
#pragma unroll
    for (int ni = 0; ni < 4; ++ni)
#pragma unroll
      for (int r = 0; r < 4; ++r) {
        int row = bm + wm + mi * 16 + quad * 4 + r;
        int e = wn + ni * 16 + lm;
        O[(size_t)row * 2048 + h * 128 + e] = f2b(acc[mi][ni][r]);
      }
}

// ---------------- layernorm(O) * U -> T (vectorized: 8 contiguous bf16/thread) ----------------
__global__ __launch_bounds__(256) void ln_mul(
    const unsigned short* __restrict__ O,
    const unsigned short* __restrict__ U,
    const void* __restrict__ g,
    const void* __restrict__ bb,
    unsigned short* __restrict__ T, const int* __restrict__ flag) {
  const bool f32 = is_f32(flag);
  const int row = blockIdx.x;
  const int t = threadIdx.x;
  const size_t base = (size_t)row * 2048 + t * 8;
  union { uint4 u; unsigned short s[8]; } vo, vu;
  vo.u = *(const uint4*)(O + base);
  float vals[8];
  float s = 0.f, s2 = 0.f;
#pragma unroll
  for (int j = 0; j < 8; ++j) {
    float f = b2f(vo.s[j]);
    vals[j] = f;
    s += f;
    s2 += f * f;
  }
#pragma unroll
  for (int off = 32; off > 0; off >>= 1) {
    s += __shfl_down(s, off, 64);
    s2 += __shfl_down(s2, off, 64);
  }
  __shared__ float ps[4], ps2[4];
  int lane = t & 63, wave = t >> 6;
  if (lane == 0) { ps[wave] = s; ps2[wave] = s2; }
  __syncthreads();
  float S = ps[0] + ps[1] + ps[2] + ps[3];
  float S2 = ps2[0] + ps2[1] + ps2[2] + ps2[3];
  float mu = S * (1.f / 2048.f);
  float var = S2 * (1.f / 2048.f) - mu * mu;
  float rs = rsqrtf(var + 1e-5f);
  vu.u = *(const uint4*)(U + base);
  float gv[8], bv[8];
  if (f32) {
    float4 g0 = *(const float4*)((const float*)g + t * 8);
    float4 g1 = *(const float4*)((const float*)g + t * 8 + 4);
    float4 b0 = *(const float4*)((const float*)bb + t * 8);
    float4 b1 = *(const float4*)((const float*)bb + t * 8 + 4);
    gv[0] = g0.x; gv[1] = g0.y; gv[2] = g0.z; gv[3] = g0.w;
    gv[4] = g1.x; gv[5] = g1.y; gv[6] = g1.z; gv[7] = g1.w;
    bv[0] = b0.x; bv[1] = b0.y; bv[2] = b0.z; bv[3] = b0.w;
    bv[4] = b1.x; bv[5] = b1.y; bv[6] = b1.z; bv[7] = b1.w;
  } else {
    union { uint4 u; unsigned short s[8]; } vg, vb;
    vg.u = *(const uint4*)((const unsigned short*)g + t * 8);
    vb.u = *(const uint4*)((const unsigned short*)bb + t * 8);
#pragma unroll
    for (int j = 0; j < 8; ++j) { gv[j] = b2f(vg.s[j]); bv[j] = b2f(vb.s[j]); }
  }
  unsigned short outp[8];
#pragma unroll
  for (int j = 0; j < 8; ++j) {
    float nv = (vals[j] - mu) * rs * gv[j] + bv[j];
    outp[j] = f2b(nv * b2f(vu.s[j]));
  }
  *(uint4*)(T + base) = *(uint4*)outp;
}

extern "C" void kernel_launch(void* const* d_in, const int* in_sizes, int n_in,
                              void* d_out, int out_size, void* d_ws, size_t ws_size,
                              hipStream_t stream) {
  const void* x   = d_in[0];
  const void* Wqk = d_in[1];
  const void* bqk = d_in[2];
  const void* Wv  = d_in[3];
  const void* bv  = d_in[4];
  const void* Wu  = d_in[5];
  const void* bu  = d_in[6];
  const void* Wo  = d_in[7];
  const void* bo  = d_in[8];
  const void* lng = d_in[9];
  const void* lnb = d_in[10];

  char* ws = (char*)d_ws;
  const size_t MB = 1024 * 1024;
  int* flag = (int*)ws;                                    // [0, 1MB)
  unsigned short* WT   = (unsigned short*)(ws + 1 * MB);   // 8 MiB (reused 4x)
  unsigned short* kvb  = (unsigned short*)(ws + 12 * MB);  // 2 MiB bf16 kv
  unsigned short* buf0 = (unsigned short*)(ws + 16 * MB);  // 64 MiB: EK -> U
  unsigned short* buf1 = (unsigned short*)(ws + 80 * MB);  // 64 MiB: VT -> O -> T
  float* kvT = (float*)(ws + 144 * MB);                    // 4 MiB
  unsigned short* xb  = (unsigned short*)(ws + 148 * MB);  // 64 MiB (f32 path only)
  unsigned short* EKT = (unsigned short*)(ws + 212 * MB);  // 64 MiB: EK transposed

  dim3 tb(256);
  dim3 gb(1024);
  dim3 ggrid(8, 64);  // (N/256, M/256)
  hipMemsetAsync(flag, 0, 4096, stream);
  hipMemsetAsync(kvT, 0, (size_t)64 * 128 * 128 * 4, stream);
  detect_dtype<<<1, tb, 0, stream>>>((const unsigned int*)x, flag);
  convert_x<<<16384, tb, 0, stream>>>(x, xb, flag);

  const unsigned short* xs = (const unsigned short*)x;
  // EK = elu(x @ Wqk + bqk); writes EK (n-major, for attn_out) AND EKT (d-major, for kv)
  transpose2048<<<dim3(64, 64), tb, 0, stream>>>(Wqk, WT, flag);
  gemm256<<<ggrid, gb, 0, stream>>>(xs, xb, 1, WT, bqk, buf0, 0, EKT, 1, 2048, 2048, 2, flag);
  // VT = silu(x @ Wv + bv)^T  (transposed only — V has no other consumer)
  transpose2048<<<dim3(64, 64), tb, 0, stream>>>(Wv, WT, flag);
  gemm256<<<ggrid, gb, 0, stream>>>(xs, xb, 1, WT, bv, buf1, 0, buf1, 2, 2048, 2048, 1, flag);
  // kv = EK^T V via mini-gemm on EKT/VT
  kv_accum<<<dim3(64, 8), tb, 0, stream>>>(EKT, buf1, kvT, 512);
  kv_to_bf16<<<512, tb, 0, stream>>>(kvT, kvb);
  // O = EK @ kv  (overwrites buf1; kv_accum already consumed VT)
  attn_out<<<dim3(16, 128), tb, 0, stream>>>(buf0, kvb, buf1);
  // U = silu(x @ Wu + bu)  (overwrites EK buffer)
  transpose2048<<<dim3(64, 64), tb, 0, stream>>>(Wu, WT, flag);
  gemm256<<<ggrid, gb, 0, stream>>>(xs, xb, 1, WT, bu, buf0, 0, EKT, 0, 2048, 2048, 1, flag);
  // T = layernorm(O) * U  (in place over O)
  ln_mul<<<16384, tb, 0, stream>>>(buf1, buf0, lng, lnb, buf1, flag);
  // out = T @ Wo + bo
  transpose2048<<<dim3(64, 64), tb, 0, stream>>>(Wo, WT, flag);
  gemm256<<<ggrid, gb, 0, stream>>>(buf1, buf1, 0, WT, bo, d_out, 1, EKT, 0, 2048, 2048, 0, flag);
}

// Round 8
// 1048.345 us; speedup vs baseline: 1.2706x; 1.0325x over previous
//
#include <hip/hip_runtime.h>

typedef __attribute__((ext_vector_type(8))) short short8;
typedef __attribute__((ext_vector_type(4))) float floatx4;

__device__ __forceinline__ float b2f(unsigned short u) {
  union { unsigned int i; float f; } c; c.i = ((unsigned int)u) << 16; return c.f;
}
__device__ __forceinline__ unsigned short f2b(float f) {
  union { float f; unsigned int i; } c; c.f = f;
  unsigned int i = c.i;
  return (unsigned short)((i + 0x7FFFu + ((i >> 16) & 1u)) >> 16);
}
__device__ __forceinline__ float elu_f(float x) {
  return x > 0.f ? x : (expf(x) - 1.f);
}
__device__ __forceinline__ float silu_f(float x) {
  return x / (1.f + expf(-x));
}
__device__ __forceinline__ void async16(const unsigned short* g, unsigned short* l) {
  __builtin_amdgcn_global_load_lds(
      (const __attribute__((address_space(1))) void*)g,
      (__attribute__((address_space(3))) void*)l, 16, 0, 0);
}
__device__ __forceinline__ floatx4 mfma16(short8 a, short8 b, floatx4 c) {
  return __builtin_amdgcn_mfma_f32_16x16x32_bf16(a, b, c, 0, 0, 0);
}

// ---------------- dtype detector ----------------
__global__ __launch_bounds__(256) void detect_dtype(
    const unsigned int* __restrict__ x, int* __restrict__ cnt) {
  int t = threadIdx.x;
  int c = 0;
  for (int i = t; i < 4096; i += 256) {
    unsigned int lo = x[i] & 0xFFFFu;
    unsigned int e = (lo >> 7) & 0xFFu;
    if (e >= 0x70u && e <= 0x8Fu) c++;
  }
#pragma unroll
  for (int off = 32; off > 0; off >>= 1) c += __shfl_down(c, off, 64);
  if ((t & 63) == 0) atomicAdd(cnt, c);
}
__device__ __forceinline__ bool is_f32(const int* flag) { return flag[0] < 2048; }

// ---------------- x -> bf16 normalize (only writes on f32 path) ----------------
__global__ __launch_bounds__(256) void convert_x(
    const void* __restrict__ x, unsigned short* __restrict__ xb,
    const int* __restrict__ flag) {
  if (!is_f32(flag)) return;
  size_t i = ((size_t)blockIdx.x * 256 + threadIdx.x) * 8;
  const float* xf = (const float*)x;
  float4 a = *(const float4*)(xf + i);
  float4 b = *(const float4*)(xf + i + 4);
  unsigned short p[8] = {f2b(a.x), f2b(a.y), f2b(a.z), f2b(a.w),
                         f2b(b.x), f2b(b.y), f2b(b.z), f2b(b.w)};
  *(uint4*)(xb + i) = *(uint4*)p;
}

// ---------------- weight transpose (2048x2048) -> bf16 ----------------
__global__ __launch_bounds__(256) void transpose2048(
    const void* __restrict__ src, unsigned short* __restrict__ dst,
    const int* __restrict__ flag) {
  const bool f32 = is_f32(flag);
  __shared__ unsigned short tile[32][33];
  int bx = blockIdx.x * 32;
  int by = blockIdx.y * 32;
  int tx = threadIdx.x & 31;
  int ty = threadIdx.x >> 5;
  for (int i = ty; i < 32; i += 8) {
    size_t idx = (size_t)(by + i) * 2048 + bx + tx;
    tile[i][tx] = f32 ? f2b(((const float*)src)[idx]) : ((const unsigned short*)src)[idx];
  }
  __syncthreads();
  for (int i = ty; i < 32; i += 8)
    dst[(size_t)(bx + i) * 2048 + by + tx] = tile[tx][i];
}

// ---------------- GEMM 256x256 tile, 1024 threads (16 waves, 4 waves/SIMD) ----------------
// C = act(A @ WT^T + bias).  act: 0=none, 1=silu, 2=elu.
// R5-proven body (153 us, MfmaUtil 39).  wtr: 0=C only; 1=C and CT; 2=CT only.
// R7 LESSON: the LDS-bounce transposed store read ot column-wise (64 scalar
// ds_read_u16/thread, ~8-way conflicts, 1.57e7 counted) and cost +60us/gemm.
// R8: CT is stored DIRECTLY from acc — lane's acc[mi][ni][r] r=0..3 are 4
// consecutive m at fixed col, i.e. one contiguous uint2 of CT[col][m].  No
// LDS pass, no conflicts; consecutive mi stores fill adjacent 32B of the same
// lines back-to-back (L2 write-combine).
__global__ __launch_bounds__(1024) void gemm256(
    const unsigned short* __restrict__ A0,
    const unsigned short* __restrict__ A1, int a_sel,
    const unsigned short* __restrict__ WT,
    const void* __restrict__ bias,
    void* __restrict__ C, int c_ext,
    unsigned short* __restrict__ CT, int wtr,
    int K, int Nc, int act, const int* __restrict__ flag) {
  const bool f32 = is_f32(flag);
  const unsigned short* A = (a_sel && f32) ? A1 : A0;
  __shared__ __align__(16) unsigned short lds[8 * 8192];  // 128 KiB
#define CH(b, m, ks) (lds + ((((b)*2 + (m)) * 2 + (ks)) * 8192))
  const int nbx = gridDim.x;                 // 8
  const int flat = blockIdx.y * nbx + blockIdx.x;
  const int nwg = nbx * gridDim.y;           // 512, divisible by 8
  const int cpx = nwg >> 3;
  const int nf = (flat & 7) * cpx + (flat >> 3);
  const int bn = (nf % nbx) * 256;
  const int bm = (nf / nbx) * 256;
  const int t = threadIdx.x;
  const int lane = t & 63;
  const int wave = t >> 6;            // 0..15
  const int lm = lane & 15;
  const int quad = lane >> 4;
  const int wm = (wave >> 2) * 64;    // 4 M-groups of 64
  const int wn = (wave & 3) * 64;     // 4 N-groups of 64
  const int srow = lane >> 2;         // staging: 4 lanes per 32-col row
  const int scol = (((lane & 3) ^ ((lane >> 3) & 3)) * 8);
  const int rq = (quad ^ ((lm >> 1) & 3)) * 8;
  const int NT = K >> 6;

  floatx4 acc[4][4] = {};

  auto stageA = [&](int kt, int ks, unsigned short* ch) {
    int rr = wave * 16;
    async16(A + (size_t)(bm + rr + srow) * K + kt + ks * 32 + scol, ch + rr * 32);
  };
  auto stageB = [&](int kt, int ks, unsigned short* ch) {
    int rr = wave * 16;
    async16(WT + (size_t)(bn + rr + srow) * K + kt + ks * 32 + scol, ch + rr * 32);
  };

  // prologue: stage tile 0 into buffer 0
  stageA(0, 0, CH(0, 0, 0));
  stageB(0, 0, CH(0, 1, 0));
  stageA(0, 1, CH(0, 0, 1));
  stageB(0, 1, CH(0, 1, 1));
  asm volatile("s_waitcnt vmcnt(0)" ::: "memory");
  asm volatile("s_barrier" ::: "memory");

  for (int ti = 0; ti < NT; ++ti) {
    const int buf = ti & 1, nb = buf ^ 1;
    const int ktn = (ti + 1 < NT ? ti + 1 : ti) << 6;

    stageA(ktn, 0, CH(nb, 0, 0));
    stageB(ktn, 0, CH(nb, 1, 0));
    stageA(ktn, 1, CH(nb, 0, 1));
    stageB(ktn, 1, CH(nb, 1, 1));

#pragma unroll
    for (int ks = 0; ks < 2; ++ks) {
      const unsigned short* cA = CH(buf, 0, ks);
      const unsigned short* cB = CH(buf, 1, ks);
      short8 af[4], bf[4];
#pragma unroll
      for (int mi = 0; mi < 4; ++mi)
        af[mi] = *(const short8*)(cA + (wm + mi * 16 + lm) * 32 + rq);
#pragma unroll
      for (int ni = 0; ni < 4; ++ni)
        bf[ni] = *(const short8*)(cB + (wn + ni * 16 + lm) * 32 + rq);
#pragma unroll
      for (int mi = 0; mi < 4; ++mi)
#pragma unroll
        for (int ni = 0; ni < 4; ++ni)
          acc[mi][ni] = mfma16(af[mi], bf[ni], acc[mi][ni]);
    }

    asm volatile("s_waitcnt vmcnt(0)" ::: "memory");
    asm volatile("s_barrier" ::: "memory");
  }

  // ---- epilogue ----
  if (c_ext && f32) {
#pragma unroll
    for (int ni = 0; ni < 4; ++ni) {
      int col = bn + wn + ni * 16 + lm;
      float bv = ((const float*)bias)[col];
#pragma unroll
      for (int mi = 0; mi < 4; ++mi) {
#pragma unroll
        for (int r = 0; r < 4; ++r) {
          int row = bm + wm + mi * 16 + quad * 4 + r;
          float v = acc[mi][ni][r] + bv;
          if (act == 1) v = silu_f(v);
          else if (act == 2) v = elu_f(v);
          ((float*)C)[(size_t)row * Nc + col] = v;
        }
      }
    }
  } else {
    // bf16 path: activated values computed once; C via LDS bounce (coalesced
    // row stores), CT directly from acc (uint2 of 4 consecutive m per lane).
    unsigned short* ot = lds;
#pragma unroll
    for (int ni = 0; ni < 4; ++ni) {
      int col = wn + ni * 16 + lm;
      float bv = f32 ? ((const float*)bias)[bn + col]
                     : b2f(((const unsigned short*)bias)[bn + col]);
#pragma unroll
      for (int mi = 0; mi < 4; ++mi) {
        int rbase = wm + mi * 16 + quad * 4;
        union { unsigned long long u; unsigned short s[4]; } p;
#pragma unroll
        for (int r = 0; r < 4; ++r) {
          float v = acc[mi][ni][r] + bv;
          if (act == 1) v = silu_f(v);
          else if (act == 2) v = elu_f(v);
          p.s[r] = f2b(v);
        }
        if (wtr != 2) {
#pragma unroll
          for (int r = 0; r < 4; ++r)
            ot[(rbase + r) * 256 + (col ^ (quad << 4))] = p.s[r];
        }
        if (wtr != 0)
          *(unsigned long long*)(CT + (size_t)(bn + col) * 16384 + bm + rbase) = p.u;
      }
    }
    if (wtr != 2) {
      __syncthreads();
      unsigned short* Cs = (unsigned short*)C;
#pragma unroll
      for (int i = 0; i < 8; ++i) {
        int c = t + 1024 * i;   // 8192 chunk ids (256 rows x 32 chunks of 16B)
        int row = c >> 5;
        int k = c & 31;
        int phys = (k * 8) ^ (((row >> 2) & 3) << 4);
        uint4 v = *(const uint4*)&ot[row * 256 + phys];
        *(uint4*)(Cs + (size_t)(bm + row) * Nc + bn + k * 8) = v;
      }
    }
  }
#undef CH
}

// ---------------- kv accumulation (mini-gemm): kvT[bh][e][d] += sum_n EKT[d][m] * VT[e][m] ----------------
// EKT/VT are [2048][16384] bf16 (transposed activations from the gemm CT path).
// Block (bh, sp): 256 threads, 4 waves (2d x 2e of 64x64), K-dim = n (chunk per sp).
__global__ __launch_bounds__(256) void kv_accum(
    const unsigned short* __restrict__ EKT,
    const unsigned short* __restrict__ VT,
    float* __restrict__ kvT, int chunk) {
  const int bh = blockIdx.x;
  const int sp = blockIdx.y;
  const int b = bh >> 4, h = bh & 15;
  __shared__ __align__(16) unsigned short lds[8 * 4096];  // 64 KiB
#define KCH(bu, m, ks) (lds + ((((bu)*2 + (m)) * 2 + (ks)) * 4096))
  const int t = threadIdx.x;
  const int lane = t & 63, wave = t >> 6;
  const int lm = lane & 15, quad = lane >> 4;
  const int wm = (wave >> 1) * 64, wn = (wave & 1) * 64;
  const int srow = lane >> 2;
  const int scol = (((lane & 3) ^ ((lane >> 3) & 3)) * 8);
  const int rq = (quad ^ ((lm >> 1) & 3)) * 8;
  floatx4 acc[4][4] = {};
  const int n0base = sp * chunk + b * 4096;   // column (m) offset
  const int NI = chunk >> 6;

  auto stage = [&](const unsigned short* src, int n0, int ks, unsigned short* ch) {
#pragma unroll
    for (int c = 0; c < 2; ++c) {
      int rr = c * 64 + wave * 16;
      async16(src + (size_t)(h * 128 + rr + srow) * 16384 + n0 + ks * 32 + scol,
              ch + rr * 32);
    }
  };

  stage(EKT, n0base, 0, KCH(0, 0, 0));
  stage(VT,  n0base, 0, KCH(0, 1, 0));
  stage(EKT, n0base, 1, KCH(0, 0, 1));
  stage(VT,  n0base, 1, KCH(0, 1, 1));
  asm volatile("s_waitcnt vmcnt(0)" ::: "memory");
  asm volatile("s_barrier" ::: "memory");

  for (int ti = 0; ti < NI; ++ti) {
    const int buf = ti & 1, nb = buf ^ 1;
    const int nn = n0base + ((ti + 1 < NI ? ti + 1 : ti) << 6);
    stage(EKT, nn, 0, KCH(nb, 0, 0));
    stage(VT,  nn, 0, KCH(nb, 1, 0));
    stage(EKT, nn, 1, KCH(nb, 0, 1));
    stage(VT,  nn, 1, KCH(nb, 1, 1));
#pragma unroll
    for (int ks = 0; ks < 2; ++ks) {
      const unsigned short* cA = KCH(buf, 0, ks);
      const unsigned short* cB = KCH(buf, 1, ks);
      short8 af[4], bf[4];
#pragma unroll
      for (int mi = 0; mi < 4; ++mi)
        af[mi] = *(const short8*)(cA + (wm + mi * 16 + lm) * 32 + rq);
#pragma unroll
      for (int ni = 0; ni < 4; ++ni)
        bf[ni] = *(const short8*)(cB + (wn + ni * 16 + lm) * 32 + rq);
#pragma unroll
      for (int mi = 0; mi < 4; ++mi)
#pragma unroll
        for (int ni = 0; ni < 4; ++ni)
          acc[mi][ni] = mfma16(af[mi], bf[ni], acc[mi][ni]);
    }
    asm volatile("s_waitcnt vmcnt(0)" ::: "memory");
    asm volatile("s_barrier" ::: "memory");
  }

  float* dst = kvT + (size_t)bh * 128 * 128;
#pragma unroll
  for (int mi = 0; mi < 4; ++mi)
#pragma unroll
    for (int ni = 0; ni < 4; ++ni)
#pragma unroll
      for (int r = 0; r < 4; ++r) {
        int d = wm + mi * 16 + quad * 4 + r;
        int e = wn + ni * 16 + lm;
        atomicAdd(&dst[e * 128 + d], acc[mi][ni][r]);
      }
#undef KCH
}

// ---------------- kvT f32 -> bf16 (once; attn_out then stages pure copies) ----------------
__global__ __launch_bounds__(256) void kv_to_bf16(
    const float* __restrict__ kvT, unsigned short* __restrict__ kvb) {
  size_t i = ((size_t)blockIdx.x * 256 + threadIdx.x) * 8;
  float4 a = *(const float4*)(kvT + i);
  float4 b = *(const float4*)(kvT + i + 4);
  unsigned short p[8] = {f2b(a.x), f2b(a.y), f2b(a.z), f2b(a.w),
                         f2b(b.x), f2b(b.y), f2b(b.z), f2b(b.w)};
  *(uint4*)(kvb + i) = *(uint4*)p;
}

// ---------------- attention out: O[n, h*128+e] = sum_d EK[n,d] * kv[d,e] ----------------
__global__ __launch_bounds__(256) void attn_out(
    const unsigned short* __restrict__ EK,
    const unsigned short* __restrict__ kvb,
    unsigned short* __restrict__ O) {
  const int flat0 = blockIdx.y * 16 + blockIdx.x;
  const int nf = (flat0 & 7) * 256 + (flat0 >> 3);  // 2048 blocks, 2048%8==0
  const int h = nf & 15;
  const int bm = (nf >> 4) * 128;
  const int b = bm >> 12;
  const int bh = b * 16 + h;
  __shared__ __align__(16) unsigned short As[128][136];
  __shared__ __align__(16) unsigned short Bs[128][136];
  const int t = threadIdx.x;
  const int lane = t & 63, wave = t >> 6;
  const int lm = lane & 15, quad = lane >> 4;
  const int wm = (wave >> 1) * 64, wn = (wave & 1) * 64;
  {
    const int r0 = t >> 4;
    const int g = t & 15;
#pragma unroll
    for (int i = 0; i < 8; ++i) {
      int r = r0 + 16 * i;
      uint4 vq = *(const uint4*)(EK + (size_t)(bm + r) * 2048 + h * 128 + g * 8);
      *(uint4*)&As[r][g * 8] = vq;   // EK pre-activated: pure copy
    }
    const unsigned short* kvp = kvb + (size_t)bh * 16384;
#pragma unroll
    for (int i = 0; i < 8; ++i) {
      int c = t + 256 * i;           // 2048 chunks of 16B
      int e = c >> 4, g2 = c & 15;
      *(uint4*)&Bs[e][g2 * 8] = *(const uint4*)(kvp + e * 128 + g2 * 8);
    }
  }
  __syncthreads();
  floatx4 acc[4][4] = {};
#pragma unroll
  for (int ks = 0; ks < 4; ++ks) {
    short8 af[4], bf[4];
#pragma unroll
    for (int mi = 0; mi < 4; ++mi)
      af[mi] = *(const short8*)&As[wm + mi * 16 + lm][ks * 32 + quad * 8];
#pragma unroll
    for (int ni = 0; ni < 4; ++ni)
      bf[ni] = *(const short8*)&Bs[wn + ni * 16 + lm][ks * 32 + quad * 8];
#pragma unroll
    for (int mi = 0; mi < 4; ++mi)
#pragma unroll
      for (int ni = 0; ni < 4; ++ni)
        acc[mi][ni] = __builtin_amdgcn_mfma_f32_16x16x32_bf16(
            af[mi], bf[ni], acc[mi][ni], 0, 0, 0);
  }
#pragma unroll
  for (int mi = 0; mi < 4; ++mi)
#pragma unroll
    for (int ni = 0; ni < 4; ++ni)
#pragma unroll
      for (int r = 0; r < 4; ++r) {
        int row = bm + wm + mi * 16 + quad * 4 + r;
        int e = wn + ni * 16 + lm;
        O[(size_t)row * 2048 + h * 128 + e] = f2b(acc[mi][ni][r]);
      }
}

// ---------------- layernorm(O) * U -> T (vectorized: 8 contiguous bf16/thread) ----------------
__global__ __launch_bounds__(256) void ln_mul(
    const unsigned short* __restrict__ O,
    const unsigned short* __restrict__ U,
    const void* __restrict__ g,
    const void* __restrict__ bb,
    unsigned short* __restrict__ T, const int* __restrict__ flag) {
  const bool f32 = is_f32(flag);
  const int row = blockIdx.x;
  const int t = threadIdx.x;
  const size_t base = (size_t)row * 2048 + t * 8;
  union { uint4 u; unsigned short s[8]; } vo, vu;
  vo.u = *(const uint4*)(O + base);
  float vals[8];
  float s = 0.f, s2 = 0.f;
#pragma unroll
  for (int j = 0; j < 8; ++j) {
    float f = b2f(vo.s[j]);
    vals[j] = f;
    s += f;
    s2 += f * f;
  }
#pragma unroll
  for (int off = 32; off > 0; off >>= 1) {
    s += __shfl_down(s, off, 64);
    s2 += __shfl_down(s2, off, 64);
  }
  __shared__ float ps[4], ps2[4];
  int lane = t & 63, wave = t >> 6;
  if (lane == 0) { ps[wave] = s; ps2[wave] = s2; }
  __syncthreads();
  float S = ps[0] + ps[1] + ps[2] + ps[3];
  float S2 = ps2[0] + ps2[1] + ps2[2] + ps2[3];
  float mu = S * (1.f / 2048.f);
  float var = S2 * (1.f / 2048.f) - mu * mu;
  float rs = rsqrtf(var + 1e-5f);
  vu.u = *(const uint4*)(U + base);
  float gv[8], bv[8];
  if (f32) {
    float4 g0 = *(const float4*)((const float*)g + t * 8);
    float4 g1 = *(const float4*)((const float*)g + t * 8 + 4);
    float4 b0 = *(const float4*)((const float*)bb + t * 8);
    float4 b1 = *(const float4*)((const float*)bb + t * 8 + 4);
    gv[0] = g0.x; gv[1] = g0.y; gv[2] = g0.z; gv[3] = g0.w;
    gv[4] = g1.x; gv[5] = g1.y; gv[6] = g1.z; gv[7] = g1.w;
    bv[0] = b0.x; bv[1] = b0.y; bv[2] = b0.z; bv[3] = b0.w;
    bv[4] = b1.x; bv[5] = b1.y; bv[6] = b1.z; bv[7] = b1.w;
  } else {
    union { uint4 u; unsigned short s[8]; } vg, vb;
    vg.u = *(const uint4*)((const unsigned short*)g + t * 8);
    vb.u = *(const uint4*)((const unsigned short*)bb + t * 8);
#pragma unroll
    for (int j = 0; j < 8; ++j) { gv[j] = b2f(vg.s[j]); bv[j] = b2f(vb.s[j]); }
  }
  unsigned short outp[8];
#pragma unroll
  for (int j = 0; j < 8; ++j) {
    float nv = (vals[j] - mu) * rs * gv[j] + bv[j];
    outp[j] = f2b(nv * b2f(vu.s[j]));
  }
  *(uint4*)(T + base) = *(uint4*)outp;
}

extern "C" void kernel_launch(void* const* d_in, const int* in_sizes, int n_in,
                              void* d_out, int out_size, void* d_ws, size_t ws_size,
                              hipStream_t stream) {
  const void* x   = d_in[0];
  const void* Wqk = d_in[1];
  const void* bqk = d_in[2];
  const void* Wv  = d_in[3];
  const void* bv  = d_in[4];
  const void* Wu  = d_in[5];
  const void* bu  = d_in[6];
  const void* Wo  = d_in[7];
  const void* bo  = d_in[8];
  const void* lng = d_in[9];
  const void* lnb = d_in[10];

  char* ws = (char*)d_ws;
  const size_t MB = 1024 * 1024;
  int* flag = (int*)ws;                                    // [0, 1MB)
  unsigned short* WT   = (unsigned short*)(ws + 1 * MB);   // 8 MiB (reused 4x)
  unsigned short* kvb  = (unsigned short*)(ws + 12 * MB);  // 2 MiB bf16 kv
  unsigned short* buf0 = (unsigned short*)(ws + 16 * MB);  // 64 MiB: EK -> U
  unsigned short* buf1 = (unsigned short*)(ws + 80 * MB);  // 64 MiB: VT -> O -> T
  float* kvT = (float*)(ws + 144 * MB);                    // 4 MiB
  unsigned short* xb  = (unsigned short*)(ws + 148 * MB);  // 64 MiB (f32 path only)
  unsigned short* EKT = (unsigned short*)(ws + 212 * MB);  // 64 MiB: EK transposed

  dim3 tb(256);
  dim3 gb(1024);
  dim3 ggrid(8, 64);  // (N/256, M/256)
  hipMemsetAsync(flag, 0, 4096, stream);
  hipMemsetAsync(kvT, 0, (size_t)64 * 128 * 128 * 4, stream);
  detect_dtype<<<1, tb, 0, stream>>>((const unsigned int*)x, flag);
  convert_x<<<16384, tb, 0, stream>>>(x, xb, flag);

  const unsigned short* xs = (const unsigned short*)x;
  // EK = elu(x @ Wqk + bqk); writes EK (n-major, for attn_out) AND EKT (d-major, for kv)
  transpose2048<<<dim3(64, 64), tb, 0, stream>>>(Wqk, WT, flag);
  gemm256<<<ggrid, gb, 0, stream>>>(xs, xb, 1, WT, bqk, buf0, 0, EKT, 1, 2048, 2048, 2, flag);
  // VT = silu(x @ Wv + bv)^T  (transposed only — V has no other consumer)
  transpose2048<<<dim3(64, 64), tb, 0, stream>>>(Wv, WT, flag);
  gemm256<<<ggrid, gb, 0, stream>>>(xs, xb, 1, WT, bv, buf1, 0, buf1, 2, 2048, 2048, 1, flag);
  // kv = EK^T V via mini-gemm on EKT/VT
  kv_accum<<<dim3(64, 8), tb, 0, stream>>>(EKT, buf1, kvT, 512);
  kv_to_bf16<<<512, tb, 0, stream>>>(kvT, kvb);
  // O = EK @ kv  (overwrites buf1; kv_accum already consumed VT)
  attn_out<<<dim3(16, 128), tb, 0, stream>>>(buf0, kvb, buf1);
  // U = silu(x @ Wu + bu)  (overwrites EK buffer)
  transpose2048<<<dim3(64, 64), tb, 0, stream>>>(Wu, WT, flag);
  gemm256<<<ggrid, gb, 0, stream>>>(xs, xb, 1, WT, bu, buf0, 0, EKT, 0, 2048, 2048, 1, flag);
  // T = layernorm(O) * U  (in place over O)
  ln_mul<<<16384, tb, 0, stream>>>(buf1, buf0, lng, lnb, buf1, flag);
  // out = T @ Wo + bo
  transpose2048<<<dim3(64, 64), tb, 0, stream>>>(Wo, WT, flag);
  gemm256<<<ggrid, gb, 0, stream>>>(buf1, buf1, 0, WT, bo, d_out, 1, EKT, 0, 2048, 2048, 0, flag);
}

// Round 9
// 1006.120 us; speedup vs baseline: 1.3239x; 1.0420x over previous
//
#include <hip/hip_runtime.h>

typedef __attribute__((ext_vector_type(8))) short short8;
typedef __attribute__((ext_vector_type(4))) float floatx4;

__device__ __forceinline__ float b2f(unsigned short u) {
  union { unsigned int i; float f; } c; c.i = ((unsigned int)u) << 16; return c.f;
}
__device__ __forceinline__ unsigned short f2b(float f) {
  union { float f; unsigned int i; } c; c.f = f;
  unsigned int i = c.i;
  return (unsigned short)((i + 0x7FFFu + ((i >> 16) & 1u)) >> 16);
}
__device__ __forceinline__ float elu_f(float x) {
  return x > 0.f ? x : (expf(x) - 1.f);
}
__device__ __forceinline__ float silu_f(float x) {
  return x / (1.f + expf(-x));
}
__device__ __forceinline__ void async16(const unsigned short* g, unsigned short* l) {
  __builtin_amdgcn_global_load_lds(
      (const __attribute__((address_space(1))) void*)g,
      (__attribute__((address_space(3))) void*)l, 16, 0, 0);
}
__device__ __forceinline__ floatx4 mfma16(short8 a, short8 b, floatx4 c) {
  return __builtin_amdgcn_mfma_f32_16x16x32_bf16(a, b, c, 0, 0, 0);
}

// ---------------- dtype detector ----------------
__global__ __launch_bounds__(256) void detect_dtype(
    const unsigned int* __restrict__ x, int* __restrict__ cnt) {
  int t = threadIdx.x;
  int c = 0;
  for (int i = t; i < 4096; i += 256) {
    unsigned int lo = x[i] & 0xFFFFu;
    unsigned int e = (lo >> 7) & 0xFFu;
    if (e >= 0x70u && e <= 0x8Fu) c++;
  }
#pragma unroll
  for (int off = 32; off > 0; off >>= 1) c += __shfl_down(c, off, 64);
  if ((t & 63) == 0) atomicAdd(cnt, c);
}
__device__ __forceinline__ bool is_f32(const int* flag) { return flag[0] < 2048; }

// ---------------- x -> bf16 normalize (only writes on f32 path) ----------------
__global__ __launch_bounds__(256) void convert_x(
    const void* __restrict__ x, unsigned short* __restrict__ xb,
    const int* __restrict__ flag) {
  if (!is_f32(flag)) return;
  size_t i = ((size_t)blockIdx.x * 256 + threadIdx.x) * 8;
  const float* xf = (const float*)x;
  float4 a = *(const float4*)(xf + i);
  float4 b = *(const float4*)(xf + i + 4);
  unsigned short p[8] = {f2b(a.x), f2b(a.y), f2b(a.z), f2b(a.w),
                         f2b(b.x), f2b(b.y), f2b(b.z), f2b(b.w)};
  *(uint4*)(xb + i) = *(uint4*)p;
}

// ---------------- weight transpose (2048x2048) -> bf16 ----------------
__global__ __launch_bounds__(256) void transpose2048(
    const void* __restrict__ src, unsigned short* __restrict__ dst,
    const int* __restrict__ flag) {
  const bool f32 = is_f32(flag);
  __shared__ unsigned short tile[32][33];
  int bx = blockIdx.x * 32;
  int by = blockIdx.y * 32;
  int tx = threadIdx.x & 31;
  int ty = threadIdx.x >> 5;
  for (int i = ty; i < 32; i += 8) {
    size_t idx = (size_t)(by + i) * 2048 + bx + tx;
    tile[i][tx] = f32 ? f2b(((const float*)src)[idx]) : ((const unsigned short*)src)[idx];
  }
  __syncthreads();
  for (int i = ty; i < 32; i += 8)
    dst[(size_t)(bx + i) * 2048 + by + tx] = tile[tx][i];
}

// ---------------- GEMM 256x256 tile, 1024 threads (16 waves, 4 waves/SIMD) ----------------
// C = act(A @ WT^T + bias).  act: 0=none, 1=silu, 2=elu.
// EXACT R5 body: best-measured configuration (153 us, 898 TF, MfmaUtil 39%,
// 0 bank conflicts, VGPR 52, no spill).  History of failed variants:
//   R4 wave-parity stagger: -6% (changed WHICH chunk, not WHEN).
//   R6 all-fragment preload: -58% (compiler drained lgkmcnt under big live set).
//   R7/R8 transposed-output (wtr): producer cost > consumer saving, net -24us.
// LDS: 2 dbuf x {A,B} x {ks0,ks1} chunks of 256x32 bf16 = 128 KiB (1 block/CU).
// One vmcnt(0)+s_barrier per K-tile.  Chunk layout XOR-swizzled
// (qf = quad ^ ((row>>1)&3)): linear LDS dest for global_load_lds +
// pre-swizzled GLOBAL source + same XOR on reads.
__global__ __launch_bounds__(1024) void gemm256(
    const unsigned short* __restrict__ A0,
    const unsigned short* __restrict__ A1, int a_sel,
    const unsigned short* __restrict__ WT,
    const void* __restrict__ bias,
    void* __restrict__ C, int c_ext,
    int K, int Nc, int act, const int* __restrict__ flag) {
  const bool f32 = is_f32(flag);
  const unsigned short* A = (a_sel && f32) ? A1 : A0;
  __shared__ __align__(16) unsigned short lds[8 * 8192];  // 128 KiB
#define CH(b, m, ks) (lds + ((((b)*2 + (m)) * 2 + (ks)) * 8192))
  const int nbx = gridDim.x;                 // 8
  const int flat = blockIdx.y * nbx + blockIdx.x;
  const int nwg = nbx * gridDim.y;           // 512, divisible by 8
  const int cpx = nwg >> 3;
  const int nf = (flat & 7) * cpx + (flat >> 3);
  const int bn = (nf % nbx) * 256;
  const int bm = (nf / nbx) * 256;
  const int t = threadIdx.x;
  const int lane = t & 63;
  const int wave = t >> 6;            // 0..15
  const int lm = lane & 15;
  const int quad = lane >> 4;
  const int wm = (wave >> 2) * 64;    // 4 M-groups of 64
  const int wn = (wave & 3) * 64;     // 4 N-groups of 64
  const int srow = lane >> 2;         // staging: 4 lanes per 32-col row
  const int scol = (((lane & 3) ^ ((lane >> 3) & 3)) * 8);
  const int rq = (quad ^ ((lm >> 1) & 3)) * 8;
  const int NT = K >> 6;

  floatx4 acc[4][4] = {};

  // each wave stages rows [wave*16, wave*16+16) of each 256x32 chunk
  auto stageA = [&](int kt, int ks, unsigned short* ch) {
    int rr = wave * 16;
    async16(A + (size_t)(bm + rr + srow) * K + kt + ks * 32 + scol, ch + rr * 32);
  };
  auto stageB = [&](int kt, int ks, unsigned short* ch) {
    int rr = wave * 16;
    async16(WT + (size_t)(bn + rr + srow) * K + kt + ks * 32 + scol, ch + rr * 32);
  };

  // prologue: stage tile 0 into buffer 0
  stageA(0, 0, CH(0, 0, 0));
  stageB(0, 0, CH(0, 1, 0));
  stageA(0, 1, CH(0, 0, 1));
  stageB(0, 1, CH(0, 1, 1));
  asm volatile("s_waitcnt vmcnt(0)" ::: "memory");
  asm volatile("s_barrier" ::: "memory");

  for (int ti = 0; ti < NT; ++ti) {
    const int buf = ti & 1, nb = buf ^ 1;
    const int ktn = (ti + 1 < NT ? ti + 1 : ti) << 6;

    // issue all next-tile staging first; vmcnt(0) at tile end is then ~free
    stageA(ktn, 0, CH(nb, 0, 0));
    stageB(ktn, 0, CH(nb, 1, 0));
    stageA(ktn, 1, CH(nb, 0, 1));
    stageB(ktn, 1, CH(nb, 1, 1));

#pragma unroll
    for (int ks = 0; ks < 2; ++ks) {
      const unsigned short* cA = CH(buf, 0, ks);
      const unsigned short* cB = CH(buf, 1, ks);
      short8 af[4], bf[4];
#pragma unroll
      for (int mi = 0; mi < 4; ++mi)
        af[mi] = *(const short8*)(cA + (wm + mi * 16 + lm) * 32 + rq);
#pragma unroll
      for (int ni = 0; ni < 4; ++ni)
        bf[ni] = *(const short8*)(cB + (wn + ni * 16 + lm) * 32 + rq);
#pragma unroll
      for (int mi = 0; mi < 4; ++mi)
#pragma unroll
        for (int ni = 0; ni < 4; ++ni)
          acc[mi][ni] = mfma16(af[mi], bf[ni], acc[mi][ni]);
    }

    asm volatile("s_waitcnt vmcnt(0)" ::: "memory");
    asm volatile("s_barrier" ::: "memory");
  }

  // ---- epilogue ----
  if (c_ext && f32) {
#pragma unroll
    for (int ni = 0; ni < 4; ++ni) {
      int col = bn + wn + ni * 16 + lm;
      float bv = ((const float*)bias)[col];
#pragma unroll
      for (int mi = 0; mi < 4; ++mi) {
#pragma unroll
        for (int r = 0; r < 4; ++r) {
          int row = bm + wm + mi * 16 + quad * 4 + r;
          float v = acc[mi][ni][r] + bv;
          if (act == 1) v = silu_f(v);
          else if (act == 2) v = elu_f(v);
          ((float*)C)[(size_t)row * Nc + col] = v;
        }
      }
    }
  } else {
    // bf16 path: LDS bounce for full-row coalesced uint4 stores
    unsigned short* ot = lds;
#pragma unroll
    for (int ni = 0; ni < 4; ++ni) {
      int col = wn + ni * 16 + lm;
      float bv = f32 ? ((const float*)bias)[bn + col]
                     : b2f(((const unsigned short*)bias)[bn + col]);
#pragma unroll
      for (int mi = 0; mi < 4; ++mi) {
        int rbase = wm + mi * 16 + quad * 4;
#pragma unroll
        for (int r = 0; r < 4; ++r) {
          float v = acc[mi][ni][r] + bv;
          if (act == 1) v = silu_f(v);
          else if (act == 2) v = elu_f(v);
          ot[(rbase + r) * 256 + (col ^ (quad << 4))] = f2b(v);
        }
      }
    }
    __syncthreads();
    unsigned short* Cs = (unsigned short*)C;
#pragma unroll
    for (int i = 0; i < 8; ++i) {
      int c = t + 1024 * i;   // 8192 chunk ids (256 rows x 32 chunks of 16B)
      int row = c >> 5;
      int k = c & 31;
      int phys = (k * 8) ^ (((row >> 2) & 3) << 4);
      uint4 v = *(const uint4*)&ot[row * 256 + phys];
      *(uint4*)(Cs + (size_t)(bm + row) * Nc + bn + k * 8) = v;
    }
  }
#undef CH
}

// ---------------- kv accumulation: kvT[b,h][e][d] += sum_n EK[n,d] * V[n,e] ----------------
// EK = elu(x@Wqk+bqk) precomputed by the gemm epilogue (act=2): staging is a
// pure transpose copy (no elu/expf in the inner loop).  R7/R8 showed paying
// for transposed EK/V production in the gemm costs more than this staging.
__global__ __launch_bounds__(256) void kv_accum(
    const unsigned short* __restrict__ EK,
    const unsigned short* __restrict__ V,
    float* __restrict__ kvT, int chunk) {
  const int bh = blockIdx.x;
  const int sp = blockIdx.y;
  const int b = bh >> 4, h = bh & 15;
  __shared__ __align__(16) unsigned short Kt[128][72];
  __shared__ __align__(16) unsigned short Vt[128][72];
  const int t = threadIdx.x;
  const int lane = t & 63, wave = t >> 6;
  const int lm = lane & 15, quad = lane >> 4;
  const int wm = (wave >> 1) * 64, wn = (wave & 1) * 64;
  floatx4 acc[4][4] = {};
  const size_t base = (size_t)b * 4096 * 2048 + (size_t)h * 128;
  const int nl = t & 63;
  const int dg0 = t >> 6;
  for (int n0 = sp * chunk; n0 < (sp + 1) * chunk; n0 += 64) {
#pragma unroll
    for (int i = 0; i < 4; ++i) {
      int dg = dg0 + 4 * i;
      union { uint4 u; unsigned short s[8]; } vk, vv;
      vk.u = *(const uint4*)(EK + base + (size_t)(n0 + nl) * 2048 + dg * 8);
      vv.u = *(const uint4*)(V + base + (size_t)(n0 + nl) * 2048 + dg * 8);
#pragma unroll
      for (int j = 0; j < 8; ++j) {
        Kt[dg * 8 + j][nl] = vk.s[j];
        Vt[dg * 8 + j][nl] = vv.s[j];
      }
    }
    __syncthreads();
#pragma unroll
    for (int ks = 0; ks < 2; ++ks) {
      short8 af[4], bf[4];
#pragma unroll
      for (int mi = 0; mi < 4; ++mi)
        af[mi] = *(const short8*)&Kt[wm + mi * 16 + lm][ks * 32 + quad * 8];
#pragma unroll
      for (int ni = 0; ni < 4; ++ni)
        bf[ni] = *(const short8*)&Vt[wn + ni * 16 + lm][ks * 32 + quad * 8];
#pragma unroll
      for (int mi = 0; mi < 4; ++mi)
#pragma unroll
        for (int ni = 0; ni < 4; ++ni)
          acc[mi][ni] = __builtin_amdgcn_mfma_f32_16x16x32_bf16(
              af[mi], bf[ni], acc[mi][ni], 0, 0, 0);
    }
    __syncthreads();
  }
  float* dst = kvT + (size_t)bh * 128 * 128;
#pragma unroll
  for (int mi = 0; mi < 4; ++mi)
#pragma unroll
    for (int ni = 0; ni < 4; ++ni)
#pragma unroll
      for (int r = 0; r < 4; ++r) {
        int d = wm + mi * 16 + quad * 4 + r;
        int e = wn + ni * 16 + lm;
        atomicAdd(&dst[e * 128 + d], acc[mi][ni][r]);
      }
}

// ---------------- kvT f32 -> bf16 (once; attn_out then stages pure copies) ----------------
__global__ __launch_bounds__(256) void kv_to_bf16(
    const float* __restrict__ kvT, unsigned short* __restrict__ kvb) {
  size_t i = ((size_t)blockIdx.x * 256 + threadIdx.x) * 8;
  float4 a = *(const float4*)(kvT + i);
  float4 b = *(const float4*)(kvT + i + 4);
  unsigned short p[8] = {f2b(a.x), f2b(a.y), f2b(a.z), f2b(a.w),
                         f2b(b.x), f2b(b.y), f2b(b.z), f2b(b.w)};
  *(uint4*)(kvb + i) = *(uint4*)p;
}

// ---------------- attention out: O[n, h*128+e] = sum_d EK[n,d] * kv[d,e] ----------------
__global__ __launch_bounds__(256) void attn_out(
    const unsigned short* __restrict__ EK,
    const unsigned short* __restrict__ kvb,
    unsigned short* __restrict__ O) {
  const int flat0 = blockIdx.y * 16 + blockIdx.x;
  const int nf = (flat0 & 7) * 256 + (flat0 >> 3);  // 2048 blocks, 2048%8==0
  const int h = nf & 15;
  const int bm = (nf >> 4) * 128;
  const int b = bm >> 12;
  const int bh = b * 16 + h;
  __shared__ __align__(16) unsigned short As[128][136];
  __shared__ __align__(16) unsigned short Bs[128][136];
  const int t = threadIdx.x;
  const int lane = t & 63, wave = t >> 6;
  const int lm = lane & 15, quad = lane >> 4;
  const int wm = (wave >> 1) * 64, wn = (wave & 1) * 64;
  {
    const int r0 = t >> 4;
    const int g = t & 15;
#pragma unroll
    for (int i = 0; i < 8; ++i) {
      int r = r0 + 16 * i;
      uint4 vq = *(const uint4*)(EK + (size_t)(bm + r) * 2048 + h * 128 + g * 8);
      *(uint4*)&As[r][g * 8] = vq;   // EK pre-activated: pure copy
    }
    const unsigned short* kvp = kvb + (size_t)bh * 16384;
#pragma unroll
    for (int i = 0; i < 8; ++i) {
      int c = t + 256 * i;           // 2048 chunks of 16B
      int e = c >> 4, g2 = c & 15;
      *(uint4*)&Bs[e][g2 * 8] = *(const uint4*)(kvp + e * 128 + g2 * 8);
    }
  }
  __syncthreads();
  floatx4 acc[4][4] = {};
#pragma unroll
  for (int ks = 0; ks < 4; ++ks) {
    short8 af[4], bf[4];
#pragma unroll
    for (int mi = 0; mi < 4; ++mi)
      af[mi] = *(const short8*)&As[wm + mi * 16 + lm][ks * 32 + quad * 8];
#pragma unroll
    for (int ni = 0; ni < 4; ++ni)
      bf[ni] = *(const short8*)&Bs[wn + ni * 16 + lm][ks * 32 + quad * 8];
#pragma unroll
    for (int mi = 0; mi < 4; ++mi)
#pragma unroll
      for (int ni = 0; ni < 4; ++ni)
        acc[mi][ni] = __builtin_amdgcn_mfma_f32_16x16x32_bf16(
            af[mi], bf[ni], acc[mi][ni], 0, 0, 0);
  }
#pragma unroll
  for (int mi = 0; mi < 4; ++mi)
#pragma unroll
    for (int ni = 0; ni < 4; ++ni)
#pragma unroll
      for (int r = 0; r < 4; ++r) {
        int row = bm + wm + mi * 16 + quad * 4 + r;
        int e = wn + ni * 16 + lm;
        O[(size_t)row * 2048 + h * 128 + e] = f2b(acc[mi][ni][r]);
      }
}

// ---------------- layernorm(O) * U -> T (vectorized: 8 contiguous bf16/thread) ----------------
__global__ __launch_bounds__(256) void ln_mul(
    const unsigned short* __restrict__ O,
    const unsigned short* __restrict__ U,
    const void* __restrict__ g,
    const void* __restrict__ bb,
    unsigned short* __restrict__ T, const int* __restrict__ flag) {
  const bool f32 = is_f32(flag);
  const int row = blockIdx.x;
  const int t = threadIdx.x;
  const size_t base = (size_t)row * 2048 + t * 8;
  union { uint4 u; unsigned short s[8]; } vo, vu;
  vo.u = *(const uint4*)(O + base);
  float vals[8];
  float s = 0.f, s2 = 0.f;
#pragma unroll
  for (int j = 0; j < 8; ++j) {
    float f = b2f(vo.s[j]);
    vals[j] = f;
    s += f;
    s2 += f * f;
  }
#pragma unroll
  for (int off = 32; off > 0; off >>= 1) {
    s += __shfl_down(s, off, 64);
    s2 += __shfl_down(s2, off, 64);
  }
  __shared__ float ps[4], ps2[4];
  int lane = t & 63, wave = t >> 6;
  if (lane == 0) { ps[wave] = s; ps2[wave] = s2; }
  __syncthreads();
  float S = ps[0] + ps[1] + ps[2] + ps[3];
  float S2 = ps2[0] + ps2[1] + ps2[2] + ps2[3];
  float mu = S * (1.f / 2048.f);
  float var = S2 * (1.f / 2048.f) - mu * mu;
  float rs = rsqrtf(var + 1e-5f);
  vu.u = *(const uint4*)(U + base);
  float gv[8], bv[8];
  if (f32) {
    float4 g0 = *(const float4*)((const float*)g + t * 8);
    float4 g1 = *(const float4*)((const float*)g + t * 8 + 4);
    float4 b0 = *(const float4*)((const float*)bb + t * 8);
    float4 b1 = *(const float4*)((const float*)bb + t * 8 + 4);
    gv[0] = g0.x; gv[1] = g0.y; gv[2] = g0.z; gv[3] = g0.w;
    gv[4] = g1.x; gv[5] = g1.y; gv[6] = g1.z; gv[7] = g1.w;
    bv[0] = b0.x; bv[1] = b0.y; bv[2] = b0.z; bv[3] = b0.w;
    bv[4] = b1.x; bv[5] = b1.y; bv[6] = b1.z; bv[7] = b1.w;
  } else {
    union { uint4 u; unsigned short s[8]; } vg, vb;
    vg.u = *(const uint4*)((const unsigned short*)g + t * 8);
    vb.u = *(const uint4*)((const unsigned short*)bb + t * 8);
#pragma unroll
    for (int j = 0; j < 8; ++j) { gv[j] = b2f(vg.s[j]); bv[j] = b2f(vb.s[j]); }
  }
  unsigned short outp[8];
#pragma unroll
  for (int j = 0; j < 8; ++j) {
    float nv = (vals[j] - mu) * rs * gv[j] + bv[j];
    outp[j] = f2b(nv * b2f(vu.s[j]));
  }
  *(uint4*)(T + base) = *(uint4*)outp;
}

extern "C" void kernel_launch(void* const* d_in, const int* in_sizes, int n_in,
                              void* d_out, int out_size, void* d_ws, size_t ws_size,
                              hipStream_t stream) {
  const void* x   = d_in[0];
  const void* Wqk = d_in[1];
  const void* bqk = d_in[2];
  const void* Wv  = d_in[3];
  const void* bv  = d_in[4];
  const void* Wu  = d_in[5];
  const void* bu  = d_in[6];
  const void* Wo  = d_in[7];
  const void* bo  = d_in[8];
  const void* lng = d_in[9];
  const void* lnb = d_in[10];

  char* ws = (char*)d_ws;
  const size_t MB = 1024 * 1024;
  int* flag = (int*)ws;                                    // [0, 1MB)
  unsigned short* WT   = (unsigned short*)(ws + 1 * MB);   // 8 MiB (reused 4x)
  unsigned short* kvb  = (unsigned short*)(ws + 12 * MB);  // 2 MiB bf16 kv
  unsigned short* buf0 = (unsigned short*)(ws + 16 * MB);  // 64 MiB: EK -> U
  unsigned short* buf1 = (unsigned short*)(ws + 80 * MB);  // 64 MiB: V -> O -> T
  float* kvT = (float*)(ws + 144 * MB);                    // 4 MiB
  unsigned short* xb  = (unsigned short*)(ws + 148 * MB);  // 64 MiB (f32 path only)

  dim3 tb(256);
  dim3 gb(1024);
  dim3 ggrid(8, 64);  // (N/256, M/256)
  hipMemsetAsync(flag, 0, 4096, stream);
  hipMemsetAsync(kvT, 0, (size_t)64 * 128 * 128 * 4, stream);
  detect_dtype<<<1, tb, 0, stream>>>((const unsigned int*)x, flag);
  convert_x<<<16384, tb, 0, stream>>>(x, xb, flag);

  const unsigned short* xs = (const unsigned short*)x;
  // EK = elu(x @ Wqk + bqk)   (elu fused: Q == K, used by both kv_accum & attn_out)
  transpose2048<<<dim3(64, 64), tb, 0, stream>>>(Wqk, WT, flag);
  gemm256<<<ggrid, gb, 0, stream>>>(xs, xb, 1, WT, bqk, buf0, 0, 2048, 2048, 2, flag);
  // V = silu(x @ Wv + bv)
  transpose2048<<<dim3(64, 64), tb, 0, stream>>>(Wv, WT, flag);
  gemm256<<<ggrid, gb, 0, stream>>>(xs, xb, 1, WT, bv, buf1, 0, 2048, 2048, 1, flag);
  // kv = EK^T V
  kv_accum<<<dim3(64, 8), tb, 0, stream>>>(buf0, buf1, kvT, 512);
  kv_to_bf16<<<512, tb, 0, stream>>>(kvT, kvb);
  // O = EK @ kv  (overwrites V buffer)
  attn_out<<<dim3(16, 128), tb, 0, stream>>>(buf0, kvb, buf1);
  // U = silu(x @ Wu + bu)  (overwrites EK buffer)
  transpose2048<<<dim3(64, 64), tb, 0, stream>>>(Wu, WT, flag);
  gemm256<<<ggrid, gb, 0, stream>>>(xs, xb, 1, WT, bu, buf0, 0, 2048, 2048, 1, flag);
  // T = layernorm(O) * U  (in place over O)
  ln_mul<<<16384, tb, 0, stream>>>(buf1, buf0, lng, lnb, buf1, flag);
  // out = T @ Wo + bo
  transpose2048<<<dim3(64, 64), tb, 0, stream>>>(Wo, WT, flag);
  gemm256<<<ggrid, gb, 0, stream>>>(buf1, buf1, 0, WT, bo, d_out, 1, 2048, 2048, 0, flag);
}